// Round 2
// baseline (1176.201 us; speedup 1.0000x reference)
//
#include <hip/hip_runtime.h>
#include <math.h>

// FermiNet 1e layer, MI355X. B=4096, N=32 (16/spin), D1=ND=256, D2=32.
// Kernel A: reduce in_2e (B,32,32,32) -> rolled-concat means all2e (B,32,64).
// Kernel C: per-batch fused GEMM + means + mixed + bias + tanh + residual.
//   v2: vectorized LDS traffic (b128 weight reads, b128 A reads, float4 stores)
//       to get the inner loop off the LDS-issue pipe and onto the FMA pipe.

#define AS1 __attribute__((address_space(1)))
#define AS3 __attribute__((address_space(3)))

__device__ __forceinline__ void g2l16(const float* g, float* l) {
  __builtin_amdgcn_global_load_lds((const AS1 unsigned int*)g,
                                   (AS3 unsigned int*)l, 16, 0, 0);
}
__device__ __forceinline__ void g2l4(const float* g, float* l) {
  __builtin_amdgcn_global_load_lds((const AS1 unsigned int*)g,
                                   (AS3 unsigned int*)l, 4, 0, 0);
}

__device__ __forceinline__ float tanh_fast(float x) {
  // tanh(x) = 1 - 2/(e^{2x}+1); exact at +-inf, ~1e-6 rel err via __expf
  float e = __expf(2.0f * x);
  return 1.0f - 2.0f / (e + 1.0f);
}

// ---------------- Kernel A: 2e spin-block means ----------------
// thread t -> (bi = b*32+i, q in [0,16)); q<8: same-spin j-block, q>=8: other.
// all2e laid out (B,32,64): [same-spin mean (32) | other-spin mean (32)].
__global__ __launch_bounds__(256) void k_reduce2e(const float* __restrict__ in2e,
                                                  float* __restrict__ all2e) {
  const int t  = blockIdx.x * 256 + threadIdx.x;   // exactly B*32*16 threads
  const int q  = t & 15;
  const int bi = t >> 4;
  const int i  = bi & 31;
  const int si = i >> 4;
  const int sj = (q < 8) ? si : 1 - si;
  const int d0 = (q & 7) << 2;
  const float4* src =
      reinterpret_cast<const float4*>(in2e + (size_t)bi * 1024 + sj * 512 + d0);
  float4 a = make_float4(0.f, 0.f, 0.f, 0.f);
#pragma unroll
  for (int p = 0; p < 16; ++p) {
    float4 v = src[p * 8];                        // row stride 32 floats
    a.x += v.x; a.y += v.y; a.z += v.z; a.w += v.w;
  }
  const float s = 1.0f / 16.0f;
  reinterpret_cast<float4*>(all2e)[t] = make_float4(a.x*s, a.y*s, a.z*s, a.w*s);
}

// ---------------- Kernel C: fused per-batch layer ----------------
// block = 1 batch, 256 threads (4 waves). LDS ~78KB -> 2 blocks/CU (stage
// stalls of one block overlap compute of the other).
// K-chunks of 32 rows x 256 cols staged via global_load_lds:
//   chunks 0..15 = W_mixed (dm phase), 16..23 = W_unmixed, 24..25 = W_2e.
// Thread tile: rows i0..i0+3, cols {c0..c0+3, c0+128..c0+131} (float4 pairs).
__global__ __launch_bounds__(256, 2) void k_main(
    const float* __restrict__ in1e, const float* __restrict__ all2e,
    const float* __restrict__ Wu, const float* __restrict__ bu,
    const float* __restrict__ Wm, const float* __restrict__ W2e,
    float* __restrict__ out) {
  __shared__ float xs[32][260];     // in_1e rows, padded (stride 260 = 4*65)
  __shared__ float ys[32][68];      // all2e rows, padded (stride 68 = 4*17)
  __shared__ float wbuf[32][256];   // current weight chunk
  __shared__ float m_lds[2][256];   // spin means
  __shared__ float dm_lds[2][256];  // dense_mixed per spin
  __shared__ float bias_lds[256];

  const int t = threadIdx.x;
  const int wave = t >> 6, lane = t & 63;
  const int b = blockIdx.x;

  // ---- prologue staging (async, drained by the first barrier) ----
  {
    const float* x_src = in1e + (size_t)b * 8192;
#pragma unroll
    for (int rr = 0; rr < 8; ++rr) {
      int r = wave * 8 + rr;
      g2l16(x_src + r * 256 + lane * 4, &xs[r][0]);   // 1KB row = 64 lanes x 16B
    }
    const float* y_src = all2e + (size_t)b * 2048;
#pragma unroll
    for (int rr = 0; rr < 8; ++rr) {
      int r = wave * 8 + rr;
      g2l4(y_src + r * 64 + lane, &ys[r][0]);         // 256B row = 64 lanes x 4B
    }
    if (wave == 0) g2l16(bu + lane * 4, &bias_lds[0]);
#pragma unroll
    for (int rr = 0; rr < 8; ++rr) {                  // W_mixed chunk 0
      int r = wave * 8 + rr;
      g2l16(Wm + r * 256 + lane * 4, &wbuf[r][0]);
    }
  }
  __syncthreads();

  // ---- per-spin means of in_1e ----
  for (int idx = t; idx < 512; idx += 256) {
    const int sp = idx >> 8, k = idx & 255;
    float sum = 0.f;
#pragma unroll
    for (int ii = 0; ii < 16; ++ii) sum += xs[sp * 16 + ii][k];
    m_lds[sp][k] = sum * (1.0f / 16.0f);
  }
  __syncthreads();

  const int spm = t >> 7, c0m = (t & 127) * 2;   // dm phase: 2 cols/thread
  const int i0 = (t >> 5) << 2, c0 = (t & 31) << 2;  // main: 4 rows x 2 float4
  float dmx = 0.f, dmy = 0.f;
  float4 acc[4][2];
#pragma unroll
  for (int j = 0; j < 4; ++j) {
    acc[j][0] = make_float4(0.f, 0.f, 0.f, 0.f);
    acc[j][1] = make_float4(0.f, 0.f, 0.f, 0.f);
  }

  for (int c = 0; c < 26; ++c) {
    if (c < 16) {
      // dense_mixed: asp[sp][k] = k<256 ? m[sp][k] : m[1-sp][k-256]
      const float* mrow = (c < 8) ? &m_lds[spm][c * 32]
                                  : &m_lds[1 - spm][c * 32 - 256];
#pragma unroll
      for (int kk = 0; kk < 32; ++kk) {
        float a = mrow[kk];                          // broadcast
        float2 w = *reinterpret_cast<const float2*>(&wbuf[kk][c0m]);
        dmx = fmaf(a, w.x, dmx);
        dmy = fmaf(a, w.y, dmy);
      }
      if (c == 15) { dm_lds[spm][c0m] = dmx; dm_lds[spm][c0m + 1] = dmy; }
    } else {
      const bool isX = (c < 24);
      const int kb = isX ? (c - 16) * 32 : (c - 24) * 32;
      const float* a0 = isX ? &xs[i0][kb] : &ys[i0][kb];
      const int as = isX ? 260 : 68;
#pragma unroll
      for (int k4 = 0; k4 < 8; ++k4) {
        float4 av[4], bA[4], bB[4];
#pragma unroll
        for (int j = 0; j < 4; ++j)     // broadcast within 32-thread group
          av[j] = *reinterpret_cast<const float4*>(a0 + j * as + k4 * 4);
#pragma unroll
        for (int u = 0; u < 4; ++u) {   // contiguous b128, conflict-free
          bA[u] = *reinterpret_cast<const float4*>(&wbuf[k4 * 4 + u][c0]);
          bB[u] = *reinterpret_cast<const float4*>(&wbuf[k4 * 4 + u][c0 + 128]);
        }
#pragma unroll
        for (int u = 0; u < 4; ++u) {
#pragma unroll
          for (int j = 0; j < 4; ++j) {
            const float a = reinterpret_cast<const float*>(&av[j])[u];
            acc[j][0].x = fmaf(a, bA[u].x, acc[j][0].x);
            acc[j][0].y = fmaf(a, bA[u].y, acc[j][0].y);
            acc[j][0].z = fmaf(a, bA[u].z, acc[j][0].z);
            acc[j][0].w = fmaf(a, bA[u].w, acc[j][0].w);
            acc[j][1].x = fmaf(a, bB[u].x, acc[j][1].x);
            acc[j][1].y = fmaf(a, bB[u].y, acc[j][1].y);
            acc[j][1].z = fmaf(a, bB[u].z, acc[j][1].z);
            acc[j][1].w = fmaf(a, bB[u].w, acc[j][1].w);
          }
        }
      }
    }
    __syncthreads();                 // everyone done reading wbuf
    if (c < 25) {
      const int cn = c + 1;
      const float* src = (cn < 16) ? (Wm + cn * 8192)
                       : (cn < 24) ? (Wu + (cn - 16) * 8192)
                                   : (W2e + (cn - 24) * 8192);
#pragma unroll
      for (int rr = 0; rr < 8; ++rr) {
        int r = wave * 8 + rr;
        g2l16(src + r * 256 + lane * 4, &wbuf[r][0]);
      }
      __syncthreads();               // stage complete (vmcnt drained)
    }
  }

  // ---- epilogue: + bias + dm, tanh, residual, store (float4) ----
  const int sp = i0 >> 4;            // spin of this thread's 4 rows
  float4 bias0 = *reinterpret_cast<const float4*>(&bias_lds[c0]);
  float4 bias1 = *reinterpret_cast<const float4*>(&bias_lds[c0 + 128]);
  float4 dm0 = *reinterpret_cast<const float4*>(&dm_lds[sp][c0]);
  float4 dm1 = *reinterpret_cast<const float4*>(&dm_lds[sp][c0 + 128]);
  float4 cadd0 = make_float4(bias0.x + dm0.x, bias0.y + dm0.y,
                             bias0.z + dm0.z, bias0.w + dm0.w);
  float4 cadd1 = make_float4(bias1.x + dm1.x, bias1.y + dm1.y,
                             bias1.z + dm1.z, bias1.w + dm1.w);
#pragma unroll
  for (int j = 0; j < 4; ++j) {
    const int row = i0 + j;
    float* orow = out + (size_t)b * 8192 + row * 256;
    float4 r0 = *reinterpret_cast<const float4*>(&xs[row][c0]);
    float4 r1 = *reinterpret_cast<const float4*>(&xs[row][c0 + 128]);
    float4 v0, v1;
    v0.x = tanh_fast(acc[j][0].x + cadd0.x) + r0.x;
    v0.y = tanh_fast(acc[j][0].y + cadd0.y) + r0.y;
    v0.z = tanh_fast(acc[j][0].z + cadd0.z) + r0.z;
    v0.w = tanh_fast(acc[j][0].w + cadd0.w) + r0.w;
    v1.x = tanh_fast(acc[j][1].x + cadd1.x) + r1.x;
    v1.y = tanh_fast(acc[j][1].y + cadd1.y) + r1.y;
    v1.z = tanh_fast(acc[j][1].z + cadd1.z) + r1.z;
    v1.w = tanh_fast(acc[j][1].w + cadd1.w) + r1.w;
    *reinterpret_cast<float4*>(orow + c0) = v0;
    *reinterpret_cast<float4*>(orow + c0 + 128) = v1;
  }
}

extern "C" void kernel_launch(void* const* d_in, const int* in_sizes, int n_in,
                              void* d_out, int out_size, void* d_ws, size_t ws_size,
                              hipStream_t stream) {
  const float* in1e = (const float*)d_in[0];   // (4096,32,256)
  const float* in2e = (const float*)d_in[1];   // (4096,32,32,32)
  const float* Wu   = (const float*)d_in[2];   // (256,256)
  const float* bu   = (const float*)d_in[3];   // (256,)
  const float* Wm   = (const float*)d_in[4];   // (512,256)
  const float* W2e  = (const float*)d_in[5];   // (64,256)
  float* out   = (float*)d_out;                // (4096,32,256)
  float* all2e = (float*)d_ws;                 // (4096,32,64) = 32MB scratch

  hipLaunchKernelGGL(k_reduce2e, dim3(8192), dim3(256), 0, stream, in2e, all2e);
  hipLaunchKernelGGL(k_main, dim3(4096), dim3(256), 0, stream,
                     in1e, all2e, Wu, bu, Wm, W2e, out);
}

// Round 3
// 1004.549 us; speedup vs baseline: 1.1709x; 1.1709x over previous
//
#include <hip/hip_runtime.h>
#include <math.h>

// FermiNet 1e layer, MI355X (gfx950). B=4096, N=32 (16/spin), D1=ND=256, D2=32.
// k_A: in_2e block-means + in_1e spin-means (single pass over both inputs).
// k_P: pack [Wu;W2e] (K=320) into MFMA-frag-major split-bf16 (hi+lo).
// k_B: dense_mixed (B,2,256) = concat-means @ Wm, amortized over 8 batches/block.
// k_C: per-batch GEMM via v_mfma_f32_32x32x16_bf16 (3-term hi/lo split),
//      double-buffered weight staging, 1 barrier/k-step, fused epilogue.

#define AS1 __attribute__((address_space(1)))
#define AS3 __attribute__((address_space(3)))

typedef __attribute__((ext_vector_type(8))) short bf16x8;
typedef __attribute__((ext_vector_type(16))) float f32x16;

__device__ __forceinline__ void g2l16(const void* g, void* l) {
  __builtin_amdgcn_global_load_lds((const AS1 unsigned int*)g,
                                   (AS3 unsigned int*)l, 16, 0, 0);
}

__device__ __forceinline__ unsigned short f2bf(float f) {  // RNE bf16
  unsigned u = __float_as_uint(f);
  u += 0x7FFFu + ((u >> 16) & 1u);
  return (unsigned short)(u >> 16);
}
__device__ __forceinline__ float bf2f(unsigned short h) {
  return __uint_as_float(((unsigned)h) << 16);
}

__device__ __forceinline__ float tanh_fast(float x) {
  float e = __expf(2.0f * x);
  return 1.0f - 2.0f / (e + 1.0f);
}

// ws layout (bytes)
#define OFF_ALL2E 0u                    // 4096*32*64 f32   = 33554432
#define OFF_MEANS 33554432u             // 4096*2*256 f32   =  8388608
#define OFF_DM    41943040u             // 4096*2*256 f32   =  8388608
#define OFF_WPK   50331648u             // 20*2*8*64*16 B   =   327680

// ---------------- k_A: 2e block means + 1e spin means ----------------
__global__ __launch_bounds__(256) void k_A(const float* __restrict__ in1e,
                                           const float* __restrict__ in2e,
                                           float* __restrict__ all2e,
                                           float* __restrict__ means) {
  const int t = threadIdx.x, b = blockIdx.x;
  // phase 1: all2e[b][i][0:32]=same-spin mean, [32:64]=other-spin mean
#pragma unroll
  for (int rep = 0; rep < 2; ++rep) {
    const int idx = rep * 256 + t;          // (i,q)
    const int q = idx & 15, i = idx >> 4;
    const int si = i >> 4;
    const int sj = (q < 8) ? si : 1 - si;
    const float4* src = reinterpret_cast<const float4*>(in2e) +
                        ((size_t)b * 8192 + i * 256 + sj * 128 + (q & 7));
    float4 a = make_float4(0.f, 0.f, 0.f, 0.f);
#pragma unroll
    for (int p = 0; p < 16; ++p) {
      float4 v = src[p * 8];
      a.x += v.x; a.y += v.y; a.z += v.z; a.w += v.w;
    }
    const float s = 1.0f / 16.0f;
    reinterpret_cast<float4*>(all2e)[(size_t)b * 512 + i * 16 + q] =
        make_float4(a.x * s, a.y * s, a.z * s, a.w * s);
  }
  // phase 2: means[b][s][k] = mean over 16 rows of spin s
#pragma unroll
  for (int rep = 0; rep < 2; ++rep) {
    const int idx = rep * 256 + t;
    const int s = idx >> 8, k = idx & 255;
    const float* base = in1e + (size_t)b * 8192 + (s * 16) * 256 + k;
    float sum = 0.f;
#pragma unroll
    for (int ii = 0; ii < 16; ++ii) sum += base[ii * 256];
    means[(size_t)b * 512 + s * 256 + k] = sum * (1.0f / 16.0f);
  }
}

// ---------------- k_P: pack split-bf16 weights, frag-major ----------------
// chunk g (16B): l=g&63, n=(g>>6)&7, v=(g>>9)&1, s=g>>10.
// holds W[k0..k0+7][c], k0 = s*16+(l>>5)*8, c = n*32+(l&31); v=0:hi, v=1:lo.
__global__ __launch_bounds__(256) void k_P(const float* __restrict__ Wu,
                                           const float* __restrict__ W2e,
                                           unsigned short* __restrict__ wpk) {
  const int g = blockIdx.x * 256 + threadIdx.x;   // 20480 chunks
  const int l = g & 63, n = (g >> 6) & 7, v = (g >> 9) & 1, s = g >> 10;
  const int c = n * 32 + (l & 31);
  const int k0 = s * 16 + (l >> 5) * 8;
  unsigned short h[8];
#pragma unroll
  for (int e = 0; e < 8; ++e) {
    const int k = k0 + e;
    const float w = (k < 256) ? Wu[k * 256 + c] : W2e[(k - 256) * 256 + c];
    const unsigned short hi = f2bf(w);
    h[e] = v ? f2bf(w - bf2f(hi)) : hi;
  }
  *reinterpret_cast<uint4*>(wpk + (size_t)g * 8) = *reinterpret_cast<uint4*>(h);
}

// ---------------- k_B: dense_mixed ----------------
// block handles 8 batches: dm[b][s][nd] = sum_k cm[b,s][k]*Wm[k][nd],
// cm = [m_s | m_{1-s}] (512). 512 blocks x 256 thr.
__global__ __launch_bounds__(256) void k_B(const float* __restrict__ means,
                                           const float* __restrict__ Wm,
                                           float* __restrict__ dm) {
  __shared__ float cm[16][512];
  const int t = threadIdx.x;
  const int b0 = blockIdx.x * 8;
#pragma unroll
  for (int j = 0; j < 32; ++j) {
    const int idx = t + 256 * j;           // 8192 elems
    const int r = idx >> 9, k = idx & 511;
    const int s = r & 1, bb = r >> 1, b = b0 + bb;
    const float mval = (k < 256) ? means[(size_t)b * 512 + s * 256 + k]
                                 : means[(size_t)b * 512 + (1 - s) * 256 + (k - 256)];
    cm[r][k] = mval;
  }
  __syncthreads();
  const int nd = t;                         // 256 cols
  float acc[16];
#pragma unroll
  for (int r = 0; r < 16; ++r) acc[r] = 0.f;
#pragma unroll 4
  for (int k = 0; k < 512; ++k) {
    const float w = Wm[(size_t)k * 256 + nd];
#pragma unroll
    for (int r = 0; r < 16; ++r) acc[r] = fmaf(cm[r][k], w, acc[r]);
  }
#pragma unroll
  for (int r = 0; r < 16; ++r) {
    const int s = r & 1, bb = r >> 1;
    dm[(size_t)(b0 + bb) * 512 + s * 256 + nd] = acc[r];
  }
}

// ---------------- k_C: main fused GEMM ----------------
// 1 batch/block, 256 thr (4 waves). K = 320 (256 from in1e + 64 from all2e).
// MFMA 32x32x16 bf16, 3-term split. 20 k-steps, wbuf double-buffered.
__global__ __launch_bounds__(256, 2) void k_C(
    const float* __restrict__ in1e, const float* __restrict__ all2e,
    const float* __restrict__ bu, const float* __restrict__ dm,
    const unsigned short* __restrict__ wpk, float* __restrict__ out) {
  __shared__ unsigned short xh[20][64][8];   // A-frags hi (20KB)
  __shared__ unsigned short xl[20][64][8];   // A-frags lo (20KB)
  __shared__ unsigned short wbuf[2][8192];   // 2 x 16KB weight k-step
  __shared__ float dmb[2][256];
  __shared__ float biasb[256];

  const int t = threadIdx.x;
  const int w = t >> 6, lane = t & 63;
  const int b = blockIdx.x;

  // -- issue async stages: wbuf[0] <- kstep 0; dm; bias --
#pragma unroll
  for (int jj = 0; jj < 4; ++jj) {
    const int cb = (jj * 4 + w) * 64;        // 16B-chunk base, wave-uniform
    g2l16((const char*)wpk + (size_t)(cb + lane) * 16, &wbuf[0][cb * 8]);
  }
  if (w == 0) {
    g2l16((const char*)(dm + (size_t)b * 512) + lane * 16, &dmb[0][0]);
  } else if (w == 1) {
    g2l16((const char*)(dm + (size_t)b * 512) + 1024 + lane * 16, &dmb[0][256]);
  } else if (w == 2) {
    g2l16((const char*)bu + lane * 16, &biasb[0]);
  }

  // -- X/Y -> split-bf16 frag-major LDS (reg-staged, converted) --
#pragma unroll
  for (int jj = 0; jj < 5; ++jj) {
    const int chunk = t + 256 * jj;          // 1280 chunks = 20 ksteps x 64 lanes
    const int s = chunk >> 6, l = chunk & 63;
    const int row = l & 31, kh = l >> 5;
    const float* gsrc;
    if (s < 16) gsrc = in1e + (size_t)b * 8192 + row * 256 + s * 16 + kh * 8;
    else        gsrc = all2e + (size_t)b * 2048 + row * 64 + (s - 16) * 16 + kh * 8;
    const float4 v0 = *reinterpret_cast<const float4*>(gsrc);
    const float4 v1 = *reinterpret_cast<const float4*>(gsrc + 4);
    float f[8] = {v0.x, v0.y, v0.z, v0.w, v1.x, v1.y, v1.z, v1.w};
    unsigned short hh[8], ll[8];
#pragma unroll
    for (int e = 0; e < 8; ++e) {
      hh[e] = f2bf(f[e]);
      ll[e] = f2bf(f[e] - bf2f(hh[e]));
    }
    *reinterpret_cast<uint4*>(&xh[s][l][0]) = *reinterpret_cast<uint4*>(hh);
    *reinterpret_cast<uint4*>(&xl[s][l][0]) = *reinterpret_cast<uint4*>(ll);
  }
  __syncthreads();   // drains g2l (vmcnt) + ds_writes (lgkm)

  // -- main loop: 20 k-steps, 1 barrier each --
  f32x16 acc0 = {}, acc1 = {};
  const int n0 = w * 2, n1 = w * 2 + 1;
  for (int s = 0; s < 20; ++s) {
    const int cur = s & 1;
    if (s < 19) {                            // stage next k-step
      const unsigned short* src = wpk + (size_t)(s + 1) * 8192;
#pragma unroll
      for (int jj = 0; jj < 4; ++jj) {
        const int cb = (jj * 4 + w) * 64;
        g2l16((const char*)src + (size_t)(cb + lane) * 16,
              &wbuf[cur ^ 1][cb * 8]);
      }
    }
    const bf16x8 ah = *reinterpret_cast<const bf16x8*>(&xh[s][lane][0]);
    const bf16x8 al = *reinterpret_cast<const bf16x8*>(&xl[s][lane][0]);
    const bf16x8 bh0 = *reinterpret_cast<const bf16x8*>(
        &wbuf[cur][((0 * 8 + n0) * 64 + lane) * 8]);
    const bf16x8 bh1 = *reinterpret_cast<const bf16x8*>(
        &wbuf[cur][((0 * 8 + n1) * 64 + lane) * 8]);
    const bf16x8 bl0 = *reinterpret_cast<const bf16x8*>(
        &wbuf[cur][((1 * 8 + n0) * 64 + lane) * 8]);
    const bf16x8 bl1 = *reinterpret_cast<const bf16x8*>(
        &wbuf[cur][((1 * 8 + n1) * 64 + lane) * 8]);
    acc0 = __builtin_amdgcn_mfma_f32_32x32x16_bf16(ah, bh0, acc0, 0, 0, 0);
    acc1 = __builtin_amdgcn_mfma_f32_32x32x16_bf16(ah, bh1, acc1, 0, 0, 0);
    acc0 = __builtin_amdgcn_mfma_f32_32x32x16_bf16(ah, bl0, acc0, 0, 0, 0);
    acc1 = __builtin_amdgcn_mfma_f32_32x32x16_bf16(ah, bl1, acc1, 0, 0, 0);
    acc0 = __builtin_amdgcn_mfma_f32_32x32x16_bf16(al, bh0, acc0, 0, 0, 0);
    acc1 = __builtin_amdgcn_mfma_f32_32x32x16_bf16(al, bh1, acc1, 0, 0, 0);
    __syncthreads();
  }

  // -- epilogue: +bias+dm, tanh, +residual, store --
  const int colA = n0 * 32 + (lane & 31);
  const int colB = n1 * 32 + (lane & 31);
  const float ca = biasb[colA], cb_ = biasb[colB];
#pragma unroll
  for (int r = 0; r < 16; ++r) {
    const int row = (r & 3) + 8 * (r >> 2) + 4 * (lane >> 5);
    const int sp = row >> 4;
    const size_t base = (size_t)b * 8192 + row * 256;
    float vA = acc0[r] + ca + dmb[sp][colA];
    float vB = acc1[r] + cb_ + dmb[sp][colB];
    vA = tanh_fast(vA) + in1e[base + colA];
    vB = tanh_fast(vB) + in1e[base + colB];
    out[base + colA] = vA;
    out[base + colB] = vB;
  }
}

extern "C" void kernel_launch(void* const* d_in, const int* in_sizes, int n_in,
                              void* d_out, int out_size, void* d_ws, size_t ws_size,
                              hipStream_t stream) {
  const float* in1e = (const float*)d_in[0];   // (4096,32,256)
  const float* in2e = (const float*)d_in[1];   // (4096,32,32,32)
  const float* Wu   = (const float*)d_in[2];   // (256,256)
  const float* bu   = (const float*)d_in[3];   // (256,)
  const float* Wm   = (const float*)d_in[4];   // (512,256)
  const float* W2e  = (const float*)d_in[5];   // (64,256)
  float* out = (float*)d_out;                  // (4096,32,256)

  char* ws = (char*)d_ws;
  float* all2e = (float*)(ws + OFF_ALL2E);
  float* means = (float*)(ws + OFF_MEANS);
  float* dm    = (float*)(ws + OFF_DM);
  unsigned short* wpk = (unsigned short*)(ws + OFF_WPK);

  hipLaunchKernelGGL(k_A, dim3(4096), dim3(256), 0, stream, in1e, in2e, all2e, means);
  hipLaunchKernelGGL(k_P, dim3(80),   dim3(256), 0, stream, Wu, W2e, wpk);
  hipLaunchKernelGGL(k_B, dim3(512),  dim3(256), 0, stream, means, Wm, dm);
  hipLaunchKernelGGL(k_C, dim3(4096), dim3(256), 0, stream, in1e, all2e, bu, dm, wpk, out);
}